// Round 2
// baseline (13312.741 us; speedup 1.0000x reference)
//
#include <hip/hip_runtime.h>
#include <hip/hip_bf16.h>

#define B_   8
#define S_   1024
#define D_   768
#define DFF_ 3072
#define L_   6
#define H_   12
#define DH_  64
#define V_   70
#define M_   (B_*S_)   // 8192 rows

typedef __attribute__((ext_vector_type(4))) float  f32x4;
typedef __attribute__((ext_vector_type(8))) short  s16x8;
typedef __attribute__((ext_vector_type(8))) __bf16 bfv8;
typedef __hip_bfloat16 bf16;

__device__ __forceinline__ float b2f(short u) {
  return __uint_as_float(((unsigned)(unsigned short)u) << 16);
}

__device__ __forceinline__ f32x4 mfma16x16x32(s16x8 a, s16x8 b, f32x4 c) {
  return __builtin_amdgcn_mfma_f32_16x16x32_bf16(
      __builtin_bit_cast(bfv8, a), __builtin_bit_cast(bfv8, b), c, 0, 0, 0);
}

// ---------------- embedding + positional encoding ----------------
__global__ __launch_bounds__(256)
void embed_kernel(const int* __restrict__ x,
                  const float* __restrict__ cW, const float* __restrict__ sW,
                  const float* __restrict__ qW, const float* __restrict__ spW,
                  float* __restrict__ hf, bf16* __restrict__ hb)
{
  int tok  = blockIdx.x;          // b*S + s
  int spos = tok & (S_ - 1);
  int t    = x[tok];
  for (int idx = threadIdx.x; idx < D_; idx += 256) {
    float e;
    if (t < 64) {
      int color = t >> 4;       if (color > 3) color = 3;
      int shp   = (t & 15) >> 2;
      int qty   = t & 3;
      e = (idx < 256) ? cW[color*256 + idx]
        : (idx < 512) ? sW[shp*256 + idx - 256]
                      : qW[qty*256 + idx - 512];
    } else {
      int sp = t - 64; if (sp > 5) sp = 5;
      e = spW[sp*D_ + idx];
    }
    int   i2  = idx & ~1;
    float ang = (float)spos * expf(-logf(10000.f) * (float)i2 / (float)D_);
    float pe  = (idx & 1) ? cosf(ang) : sinf(ang);
    float v   = e * 27.712812921102035f + pe;   // sqrt(768)
    hf[(size_t)tok*D_ + idx] = v;
    hb[(size_t)tok*D_ + idx] = __float2bfloat16(v);
  }
}

// ---------------- f32 [K,N] -> bf16 [N,K] ----------------
__global__ __launch_bounds__(256)
void transpose_kernel(const float* __restrict__ in, bf16* __restrict__ out,
                      int K, int N)
{
  __shared__ __align__(16) float s[64][65];
  int n0 = blockIdx.x * 64, k0 = blockIdx.y * 64;
  int tx = threadIdx.x & 63, ty = threadIdx.x >> 6;
  #pragma unroll
  for (int i = 0; i < 16; i++) {
    int r = i*4 + ty;
    s[r][tx] = in[(size_t)(k0 + r)*N + n0 + tx];
  }
  __syncthreads();
  #pragma unroll
  for (int i = 0; i < 16; i++) {
    int r = i*4 + ty;
    out[(size_t)(n0 + r)*K + k0 + tx] = __float2bfloat16(s[tx][r]);
  }
}

// ---------------- GEMM: C[M,N] = A[M,K] @ B, with B given as BT[N,K] --------
// 128x128 tile, BK=32, 4 waves (2x2), each wave 64x64 = 4x4 MFMA fragments.
template<bool BIAS, bool RELU, bool OUTBF16>
__global__ __launch_bounds__(256, 2)
void gemm_kernel(const bf16* __restrict__ A, const bf16* __restrict__ BT,
                 const float* __restrict__ bias,
                 float* __restrict__ Cf, bf16* __restrict__ Cb,
                 int N, int K)
{
  __shared__ __align__(16) short As[4][128][8];
  __shared__ __align__(16) short Bs[4][128][8];
  int t = threadIdx.x;
  int wave = t >> 6, lane = t & 63;
  int wr = wave >> 1, wc = wave & 1;
  int brow = blockIdx.x * 128, bcol = blockIdx.y * 128;
  int r0 = t & 127, kc = t >> 7;          // staging: row 0..127, kchunk 0..1
  const short* Ap = (const short*)A + (size_t)(brow + r0)*K + kc*8;
  const short* Bp = (const short*)BT + (size_t)(bcol + r0)*K + kc*8;
  int lr = lane & 15, kg = lane >> 4;

  f32x4 acc[4][4] = {};
  s16x8 a0 = *(const s16x8*)(Ap);
  s16x8 a1 = *(const s16x8*)(Ap + 16);
  s16x8 b0 = *(const s16x8*)(Bp);
  s16x8 b1 = *(const s16x8*)(Bp + 16);

  for (int kk = 0; kk < K; kk += 32) {
    __syncthreads();
    *(s16x8*)&As[kc  ][r0][0] = a0;
    *(s16x8*)&As[kc+2][r0][0] = a1;
    *(s16x8*)&Bs[kc  ][r0][0] = b0;
    *(s16x8*)&Bs[kc+2][r0][0] = b1;
    __syncthreads();
    if (kk + 32 < K) {                    // prefetch next K-tile into regs
      a0 = *(const s16x8*)(Ap + kk + 32);
      a1 = *(const s16x8*)(Ap + kk + 48);
      b0 = *(const s16x8*)(Bp + kk + 32);
      b1 = *(const s16x8*)(Bp + kk + 48);
    }
    s16x8 af[4], bq[4];
    #pragma unroll
    for (int m = 0; m < 4; m++) af[m] = *(const s16x8*)&As[kg][wr*64 + m*16 + lr][0];
    #pragma unroll
    for (int n = 0; n < 4; n++) bq[n] = *(const s16x8*)&Bs[kg][wc*64 + n*16 + lr][0];
    #pragma unroll
    for (int m = 0; m < 4; m++)
      #pragma unroll
      for (int n = 0; n < 4; n++)
        acc[m][n] = mfma16x16x32(af[m], bq[n], acc[m][n]);
  }

  int lg = lane >> 4;
  #pragma unroll
  for (int n = 0; n < 4; n++) {
    int col = bcol + wc*64 + n*16 + lr;
    float bv = 0.f;
    if (BIAS) bv = bias[col];
    #pragma unroll
    for (int m = 0; m < 4; m++) {
      int row0 = brow + wr*64 + m*16 + lg*4;
      #pragma unroll
      for (int r = 0; r < 4; r++) {
        float v = acc[m][n][r] + bv;
        if (RELU) v = fmaxf(v, 0.f);
        size_t off = (size_t)(row0 + r)*N + col;
        if (OUTBF16) Cb[off] = __float2bfloat16(v);
        else         Cf[off] = v;
      }
    }
  }
}

// ---------------- fused attention (vector v0, bf16 QKV) ----------------
// grid (S/16, H, B); block 256 = 4 waves; wave handles 4 query rows.
__global__ __launch_bounds__(256)
void attn_kernel(const bf16* __restrict__ Q, const bf16* __restrict__ Km,
                 const bf16* __restrict__ Vm, const int* __restrict__ mask,
                 bf16* __restrict__ O)
{
  __shared__ __align__(16) float q_lds[16][64];
  __shared__ __align__(16) bf16  p_buf[16][1024];
  int b = blockIdx.z, h = blockIdx.y;
  int q0 = blockIdx.x * 16;
  int t = threadIdx.x, wave = t >> 6, lane = t & 63;
  {
    int r = t >> 4, d0 = (t & 15) * 4;
    const short* qp = (const short*)Q + (size_t)(b*S_ + q0 + r)*D_ + h*DH_ + d0;
    short4 qv = *(const short4*)qp;
    q_lds[r][d0+0] = b2f(qv.x);
    q_lds[r][d0+1] = b2f(qv.y);
    q_lds[r][d0+2] = b2f(qv.z);
    q_lds[r][d0+3] = b2f(qv.w);
  }
  __syncthreads();
  int r0 = wave * 4;
  int qrow = q0 + r0;
  const short* Kb = (const short*)Km + (size_t)b*S_*D_ + h*DH_;
  float s[4][16];

  #pragma unroll
  for (int jg = 0; jg < 16; jg++) {
    int j = jg*64 + lane;
    const short* kp = Kb + (size_t)j*D_;
    float a0=0.f, a1=0.f, a2=0.f, a3=0.f;
    #pragma unroll
    for (int c = 0; c < 8; ++c) {
      s16x8 kv = *(const s16x8*)(kp + c*8);
      float kf[8];
      #pragma unroll
      for (int jj = 0; jj < 8; jj++) kf[jj] = b2f(kv[jj]);
      #pragma unroll
      for (int jj = 0; jj < 8; jj++) {
        a0 += q_lds[r0+0][c*8+jj] * kf[jj];
        a1 += q_lds[r0+1][c*8+jj] * kf[jj];
        a2 += q_lds[r0+2][c*8+jj] * kf[jj];
        a3 += q_lds[r0+3][c*8+jj] * kf[jj];
      }
    }
    int m0 = mask[(size_t)(qrow+0)*S_ + j];
    int m1 = mask[(size_t)(qrow+1)*S_ + j];
    int m2 = mask[(size_t)(qrow+2)*S_ + j];
    int m3 = mask[(size_t)(qrow+3)*S_ + j];
    s[0][jg] = m0 ? a0*0.125f : -1e9f;
    s[1][jg] = m1 ? a1*0.125f : -1e9f;
    s[2][jg] = m2 ? a2*0.125f : -1e9f;
    s[3][jg] = m3 ? a3*0.125f : -1e9f;
  }

  float lsum[4];
  #pragma unroll
  for (int r = 0; r < 4; r++) {
    float m = s[r][0];
    #pragma unroll
    for (int jg = 1; jg < 16; jg++) m = fmaxf(m, s[r][jg]);
    #pragma unroll
    for (int o = 1; o < 64; o <<= 1) m = fmaxf(m, __shfl_xor(m, o));
    float sum = 0.f;
    #pragma unroll
    for (int jg = 0; jg < 16; jg++) {
      float p = __expf(s[r][jg] - m);
      s[r][jg] = p;
      sum += p;
    }
    #pragma unroll
    for (int o = 1; o < 64; o <<= 1) sum += __shfl_xor(sum, o);
    lsum[r] = sum;
    #pragma unroll
    for (int jg = 0; jg < 16; jg++)
      p_buf[r0 + r][jg*64 + lane] = __float2bfloat16(s[r][jg]);
  }

  // Phase 2: PV.  lane = d.  p_buf reads are wave-local (LDS in-order per wave).
  const short* Vb = (const short*)Vm + (size_t)b*S_*D_ + h*DH_ + lane;
  float o0=0.f, o1=0.f, o2=0.f, o3=0.f;
  for (int j8 = 0; j8 < 128; j8++) {
    s16x8 p0 = *(const s16x8*)&p_buf[r0+0][j8*8];
    s16x8 p1 = *(const s16x8*)&p_buf[r0+1][j8*8];
    s16x8 p2 = *(const s16x8*)&p_buf[r0+2][j8*8];
    s16x8 p3 = *(const s16x8*)&p_buf[r0+3][j8*8];
    #pragma unroll
    for (int jj = 0; jj < 8; jj++) {
      float vv = b2f(Vb[(size_t)(j8*8 + jj)*D_]);
      o0 += b2f(p0[jj]) * vv;
      o1 += b2f(p1[jj]) * vv;
      o2 += b2f(p2[jj]) * vv;
      o3 += b2f(p3[jj]) * vv;
    }
  }
  size_t obase = (size_t)(b*S_ + qrow)*D_ + h*DH_ + lane;
  O[obase + 0*D_] = __float2bfloat16(o0 / lsum[0]);
  O[obase + 1*D_] = __float2bfloat16(o1 / lsum[1]);
  O[obase + 2*D_] = __float2bfloat16(o2 / lsum[2]);
  O[obase + 3*D_] = __float2bfloat16(o3 / lsum[3]);
}

// ---------------- residual add + layernorm (in-place on h) ----------------
__global__ __launch_bounds__(256)
void ln_kernel(float* h, const float* __restrict__ delta,
               const float* __restrict__ g, const float* __restrict__ bta,
               bf16* __restrict__ hb)
{
  int row = blockIdx.x;
  float* rp = h + (size_t)row*D_;
  const float* dp = delta + (size_t)row*D_;
  int t = threadIdx.x;
  float v[3];
  float sum = 0.f, sq = 0.f;
  #pragma unroll
  for (int i = 0; i < 3; i++) {
    float xv = rp[t + i*256] + dp[t + i*256];
    v[i] = xv; sum += xv; sq += xv*xv;
  }
  #pragma unroll
  for (int o = 1; o < 64; o <<= 1) { sum += __shfl_xor(sum, o); sq += __shfl_xor(sq, o); }
  __shared__ float ws[8];
  int wave = t >> 6, lane = t & 63;
  if (lane == 0) { ws[wave] = sum; ws[wave+4] = sq; }
  __syncthreads();
  sum = ws[0]+ws[1]+ws[2]+ws[3];
  sq  = ws[4]+ws[5]+ws[6]+ws[7];
  float m   = sum * (1.f/768.f);
  float var = sq * (1.f/768.f) - m*m;
  float rs  = rsqrtf(var + 1e-5f);
  #pragma unroll
  for (int i = 0; i < 3; i++) {
    int idx = t + i*256;
    float y = (v[i] - m) * rs * g[idx] + bta[idx];
    rp[idx] = y;
    hb[(size_t)row*D_ + idx] = __float2bfloat16(y);
  }
}

// ---------------- final projection h[M,768] @ Wout[768,70] + bout ----------
__global__ __launch_bounds__(128)
void final_kernel(const float* __restrict__ h, const float* __restrict__ Wout,
                  const float* __restrict__ bout, float* __restrict__ out)
{
  __shared__ float hs[D_];
  int row = blockIdx.x;
  for (int i = threadIdx.x; i < D_; i += 128) hs[i] = h[(size_t)row*D_ + i];
  __syncthreads();
  int n = threadIdx.x;
  if (n < V_) {
    float acc = bout[n];
    for (int d = 0; d < D_; d++) acc += hs[d] * Wout[d*V_ + n];
    out[(size_t)row*V_ + n] = acc;
  }
}

// ---------------- host launch ----------------
// Workspace budget (must fit ws_size):
//   hf 24M + delta 24M + hb 12M + ob 12M + shared 48M (qkv bf16 36M / f1 48M
//   aliased, disjoint lifetimes) + per-layer wT 14.2M  ~= 140 MB total.
extern "C" void kernel_launch(void* const* d_in, const int* in_sizes, int n_in,
                              void* d_out, int out_size, void* d_ws, size_t ws_size,
                              hipStream_t stream)
{
  (void)in_sizes; (void)n_in; (void)out_size; (void)ws_size;
  const int*   x    = (const int*)d_in[0];
  const int*   mask = (const int*)d_in[1];
  const float* cW   = (const float*)d_in[2];
  const float* sW   = (const float*)d_in[3];
  const float* qW   = (const float*)d_in[4];
  const float* spW  = (const float*)d_in[5];
  const float* Wq   = (const float*)d_in[6];
  const float* Wk   = (const float*)d_in[7];
  const float* Wv   = (const float*)d_in[8];
  const float* Wo   = (const float*)d_in[9];
  const float* bo   = (const float*)d_in[10];
  const float* ln1g = (const float*)d_in[11];
  const float* ln1b = (const float*)d_in[12];
  const float* ln2g = (const float*)d_in[13];
  const float* ln2b = (const float*)d_in[14];
  const float* W1   = (const float*)d_in[15];
  const float* b1   = (const float*)d_in[16];
  const float* W2   = (const float*)d_in[17];
  const float* b2   = (const float*)d_in[18];
  const float* Wout = (const float*)d_in[19];
  const float* bout = (const float*)d_in[20];
  float* out = (float*)d_out;

  char* p = (char*)d_ws;
  auto alloc = [&](size_t bytes) {
    char* r = p; p += (bytes + 1023) & ~(size_t)1023; return r;
  };
  float* hf     = (float*)alloc((size_t)M_*D_*4);
  float* delta  = (float*)alloc((size_t)M_*D_*4);
  bf16*  hb     = (bf16*)alloc((size_t)M_*D_*2);
  bf16*  ob     = (bf16*)alloc((size_t)M_*D_*2);
  char*  shared = alloc((size_t)M_*DFF_*2);      // f1 (48M) / qkv (36M) union
  bf16*  qb     = (bf16*)shared;
  bf16*  kb     = (bf16*)(shared + (size_t)M_*D_*2);
  bf16*  vb     = (bf16*)(shared + (size_t)2*M_*D_*2);
  bf16*  f1     = (bf16*)shared;
  bf16*  wqT    = (bf16*)alloc((size_t)D_*D_*2);
  bf16*  wkT    = (bf16*)alloc((size_t)D_*D_*2);
  bf16*  wvT    = (bf16*)alloc((size_t)D_*D_*2);
  bf16*  woT    = (bf16*)alloc((size_t)D_*D_*2);
  bf16*  w1T    = (bf16*)alloc((size_t)D_*DFF_*2);
  bf16*  w2T    = (bf16*)alloc((size_t)DFF_*D_*2);

  embed_kernel<<<M_, 256, 0, stream>>>(x, cW, sW, qW, spW, hf, hb);

  for (int l = 0; l < L_; l++) {
    // per-layer weight transposes (f32 [K,N] -> bf16 [N,K])
    transpose_kernel<<<dim3(12,12), 256, 0, stream>>>(Wq + (size_t)l*D_*D_, wqT, D_, D_);
    transpose_kernel<<<dim3(12,12), 256, 0, stream>>>(Wk + (size_t)l*D_*D_, wkT, D_, D_);
    transpose_kernel<<<dim3(12,12), 256, 0, stream>>>(Wv + (size_t)l*D_*D_, wvT, D_, D_);
    transpose_kernel<<<dim3(12,12), 256, 0, stream>>>(Wo + (size_t)l*D_*D_, woT, D_, D_);
    transpose_kernel<<<dim3(48,12), 256, 0, stream>>>(W1 + (size_t)l*D_*DFF_, w1T, D_, DFF_);
    transpose_kernel<<<dim3(12,48), 256, 0, stream>>>(W2 + (size_t)l*DFF_*D_, w2T, DFF_, D_);

    gemm_kernel<false,false,true><<<dim3(64,6), 256, 0, stream>>>(hb, wqT, nullptr, nullptr, qb, D_, D_);
    gemm_kernel<false,false,true><<<dim3(64,6), 256, 0, stream>>>(hb, wkT, nullptr, nullptr, kb, D_, D_);
    gemm_kernel<false,false,true><<<dim3(64,6), 256, 0, stream>>>(hb, wvT, nullptr, nullptr, vb, D_, D_);

    attn_kernel<<<dim3(S_/16, H_, B_), 256, 0, stream>>>(qb, kb, vb, mask, ob);

    gemm_kernel<true,false,false><<<dim3(64,6), 256, 0, stream>>>(ob, woT, bo + l*D_, delta, nullptr, D_, D_);
    ln_kernel<<<M_, 256, 0, stream>>>(hf, delta, ln1g + l*D_, ln1b + l*D_, hb);

    gemm_kernel<true,true,true ><<<dim3(64,24), 256, 0, stream>>>(hb, w1T, b1 + l*DFF_, nullptr, f1, DFF_, D_);
    gemm_kernel<true,false,false><<<dim3(64,6), 256, 0, stream>>>(f1, w2T, b2 + l*D_, delta, nullptr, D_, DFF_);
    ln_kernel<<<M_, 256, 0, stream>>>(hf, delta, ln2g + l*D_, ln2b + l*D_, hb);
  }

  final_kernel<<<M_, 128, 0, stream>>>(hf, Wout, bout, out);
}

// Round 3
// 3437.491 us; speedup vs baseline: 3.8728x; 3.8728x over previous
//
#include <hip/hip_runtime.h>
#include <hip/hip_bf16.h>

#define B_   8
#define S_   1024
#define D_   768
#define DFF_ 3072
#define L_   6
#define H_   12
#define DH_  64
#define V_   70
#define M_   (B_*S_)   // 8192 rows

typedef __attribute__((ext_vector_type(4))) float  f32x4;
typedef __attribute__((ext_vector_type(8))) short  s16x8;
typedef __attribute__((ext_vector_type(8))) __bf16 bfv8;
typedef __hip_bfloat16 bf16;

__device__ __forceinline__ float b2f(short u) {
  return __uint_as_float(((unsigned)(unsigned short)u) << 16);
}

__device__ __forceinline__ f32x4 mfma16x16x32(s16x8 a, s16x8 b, f32x4 c) {
  return __builtin_amdgcn_mfma_f32_16x16x32_bf16(
      __builtin_bit_cast(bfv8, a), __builtin_bit_cast(bfv8, b), c, 0, 0, 0);
}

// ---------------- embedding + positional encoding ----------------
__global__ __launch_bounds__(256)
void embed_kernel(const int* __restrict__ x,
                  const float* __restrict__ cW, const float* __restrict__ sW,
                  const float* __restrict__ qW, const float* __restrict__ spW,
                  float* __restrict__ hf, bf16* __restrict__ hb)
{
  int tok  = blockIdx.x;          // b*S + s
  int spos = tok & (S_ - 1);
  int t    = x[tok];
  for (int idx = threadIdx.x; idx < D_; idx += 256) {
    float e;
    if (t < 64) {
      int color = t >> 4;       if (color > 3) color = 3;
      int shp   = (t & 15) >> 2;
      int qty   = t & 3;
      e = (idx < 256) ? cW[color*256 + idx]
        : (idx < 512) ? sW[shp*256 + idx - 256]
                      : qW[qty*256 + idx - 512];
    } else {
      int sp = t - 64; if (sp > 5) sp = 5;
      e = spW[sp*D_ + idx];
    }
    int   i2  = idx & ~1;
    float ang = (float)spos * expf(-logf(10000.f) * (float)i2 / (float)D_);
    float pe  = (idx & 1) ? cosf(ang) : sinf(ang);
    float v   = e * 27.712812921102035f + pe;   // sqrt(768)
    hf[(size_t)tok*D_ + idx] = v;
    hb[(size_t)tok*D_ + idx] = __float2bfloat16(v);
  }
}

// ---------------- f32 [K,N] -> bf16 [N,K] ----------------
__global__ __launch_bounds__(256)
void transpose_kernel(const float* __restrict__ in, bf16* __restrict__ out,
                      int K, int N)
{
  __shared__ __align__(16) float s[64][65];
  int n0 = blockIdx.x * 64, k0 = blockIdx.y * 64;
  int tx = threadIdx.x & 63, ty = threadIdx.x >> 6;
  #pragma unroll
  for (int i = 0; i < 16; i++) {
    int r = i*4 + ty;
    s[r][tx] = in[(size_t)(k0 + r)*N + n0 + tx];
  }
  __syncthreads();
  #pragma unroll
  for (int i = 0; i < 16; i++) {
    int r = i*4 + ty;
    out[(size_t)(n0 + r)*K + k0 + tx] = __float2bfloat16(s[tx][r]);
  }
}

// ---------------- bf16 [b][s][h][d] -> [b][h][d][s] (V transpose) ----------
__global__ __launch_bounds__(256)
void vT_kernel(const bf16* __restrict__ v, bf16* __restrict__ vt)
{
  __shared__ short tile[64][68];
  int b = blockIdx.z, h = blockIdx.y, s0 = blockIdx.x*64;
  int tr = threadIdx.x >> 4, tc4 = (threadIdx.x & 15)*4;
  #pragma unroll
  for (int i = 0; i < 4; i++) {
    int row = i*16 + tr;
    short4 w = *(const short4*)((const short*)v + (size_t)(b*S_ + s0 + row)*D_ + h*DH_ + tc4);
    tile[row][tc4+0]=w.x; tile[row][tc4+1]=w.y; tile[row][tc4+2]=w.z; tile[row][tc4+3]=w.w;
  }
  __syncthreads();
  #pragma unroll
  for (int i = 0; i < 4; i++) {
    int d = i*16 + tr;
    short4 o2;
    o2.x = tile[tc4+0][d]; o2.y = tile[tc4+1][d]; o2.z = tile[tc4+2][d]; o2.w = tile[tc4+3][d];
    *(short4*)((short*)vt + ((size_t)(b*H_ + h)*DH_ + d)*S_ + s0 + tc4) = o2;
  }
}

// ---------------- mask -> additive bf16 bias ----------------
__global__ __launch_bounds__(256)
void maskb_kernel(const int* __restrict__ mask, bf16* __restrict__ mb)
{
  int i = (blockIdx.x*256 + threadIdx.x)*4;
  int4 mv = *(const int4*)(mask + i);
  bf16 z = __float2bfloat16(0.f), ng = __float2bfloat16(-1e9f);
  mb[i+0] = mv.x ? z : ng;
  mb[i+1] = mv.y ? z : ng;
  mb[i+2] = mv.z ? z : ng;
  mb[i+3] = mv.w ? z : ng;
}

// ---------------- GEMM: C[M,N] = A[M,K] @ B, with B given as BT[N,K] --------
template<bool BIAS, bool RELU, bool OUTBF16>
__global__ __launch_bounds__(256, 2)
void gemm_kernel(const bf16* __restrict__ A, const bf16* __restrict__ BT,
                 const float* __restrict__ bias,
                 float* __restrict__ Cf, bf16* __restrict__ Cb,
                 int N, int K)
{
  __shared__ __align__(16) short As[4][128][8];
  __shared__ __align__(16) short Bs[4][128][8];
  int t = threadIdx.x;
  int wave = t >> 6, lane = t & 63;
  int wr = wave >> 1, wc = wave & 1;
  int brow = blockIdx.x * 128, bcol = blockIdx.y * 128;
  int r0 = t & 127, kc = t >> 7;
  const short* Ap = (const short*)A + (size_t)(brow + r0)*K + kc*8;
  const short* Bp = (const short*)BT + (size_t)(bcol + r0)*K + kc*8;
  int lr = lane & 15, kg = lane >> 4;

  f32x4 acc[4][4] = {};
  s16x8 a0 = *(const s16x8*)(Ap);
  s16x8 a1 = *(const s16x8*)(Ap + 16);
  s16x8 b0 = *(const s16x8*)(Bp);
  s16x8 b1 = *(const s16x8*)(Bp + 16);

  for (int kk = 0; kk < K; kk += 32) {
    __syncthreads();
    *(s16x8*)&As[kc  ][r0][0] = a0;
    *(s16x8*)&As[kc+2][r0][0] = a1;
    *(s16x8*)&Bs[kc  ][r0][0] = b0;
    *(s16x8*)&Bs[kc+2][r0][0] = b1;
    __syncthreads();
    if (kk + 32 < K) {
      a0 = *(const s16x8*)(Ap + kk + 32);
      a1 = *(const s16x8*)(Ap + kk + 48);
      b0 = *(const s16x8*)(Bp + kk + 32);
      b1 = *(const s16x8*)(Bp + kk + 48);
    }
    s16x8 af[4], bq[4];
    #pragma unroll
    for (int m = 0; m < 4; m++) af[m] = *(const s16x8*)&As[kg][wr*64 + m*16 + lr][0];
    #pragma unroll
    for (int n = 0; n < 4; n++) bq[n] = *(const s16x8*)&Bs[kg][wc*64 + n*16 + lr][0];
    #pragma unroll
    for (int m = 0; m < 4; m++)
      #pragma unroll
      for (int n = 0; n < 4; n++)
        acc[m][n] = mfma16x16x32(af[m], bq[n], acc[m][n]);
  }

  int lg = lane >> 4;
  #pragma unroll
  for (int n = 0; n < 4; n++) {
    int col = bcol + wc*64 + n*16 + lr;
    float bv = 0.f;
    if (BIAS) bv = bias[col];
    #pragma unroll
    for (int m = 0; m < 4; m++) {
      int row0 = brow + wr*64 + m*16 + lg*4;
      #pragma unroll
      for (int r = 0; r < 4; r++) {
        float v = acc[m][n][r] + bv;
        if (RELU) v = fmaxf(v, 0.f);
        size_t off = (size_t)(row0 + r)*N + col;
        if (OUTBF16) Cb[off] = __float2bfloat16(v);
        else         Cf[off] = v;
      }
    }
  }
}

// ---------------- MFMA flash attention ----------------
// grid (S/64, H, B), 4 waves; wave owns 16 q-rows, loops KV in tiles of 64.
// Fragment conventions (same as verified gemm_kernel):
//   A-operand: row = lane&15, kdim = (lane>>4)*8 + j
//   B-operand: col = lane&15, kdim = (lane>>4)*8 + j
//   C/D:       col = lane&15, row = (lane>>4)*4 + reg
__global__ __launch_bounds__(256)
void fattn_kernel(const bf16* __restrict__ Q, const bf16* __restrict__ K,
                  const bf16* __restrict__ Vt, const bf16* __restrict__ Mb,
                  bf16* __restrict__ O)
{
  __shared__ __align__(16) bf16 p_lds[4][16][72];   // pad 72 -> 2-way (free)
  int b = blockIdx.z, h = blockIdx.y;
  int wave = threadIdx.x >> 6, lane = threadIdx.x & 63;
  int c = lane & 15, g = lane >> 4;
  int q0 = blockIdx.x*64 + wave*16;

  const short* Qp = (const short*)Q + (size_t)(b*S_ + q0 + c)*D_ + h*DH_;
  s16x8 qf0 = *(const s16x8*)(Qp + g*8);
  s16x8 qf1 = *(const s16x8*)(Qp + 32 + g*8);
  const short* Kb = (const short*)K + (size_t)(b*S_)*D_ + h*DH_;
  const short* Vb = (const short*)Vt + (size_t)(b*H_ + h)*DH_*S_;
  const short* Mp = (const short*)Mb + (size_t)(q0 + g*4)*S_;

  f32x4 o[4] = {};
  float m[4]  = {-3.0e38f, -3.0e38f, -3.0e38f, -3.0e38f};
  float l[4]  = {0.f, 0.f, 0.f, 0.f};

  for (int k0 = 0; k0 < S_; k0 += 64) {
    f32x4 s[4];
    #pragma unroll
    for (int n = 0; n < 4; n++) {
      const short* kp = Kb + (size_t)(k0 + n*16 + c)*D_;
      s16x8 kf0 = *(const s16x8*)(kp + g*8);
      s16x8 kf1 = *(const s16x8*)(kp + 32 + g*8);
      f32x4 z = {};
      z    = mfma16x16x32(qf0, kf0, z);
      s[n] = mfma16x16x32(qf1, kf1, z);
    }
    #pragma unroll
    for (int n = 0; n < 4; n++)
      #pragma unroll
      for (int r = 0; r < 4; r++)
        s[n][r] = s[n][r]*0.125f + b2f(Mp[(size_t)r*S_ + k0 + n*16 + c]);

    float tm[4];
    #pragma unroll
    for (int r = 0; r < 4; r++)
      tm[r] = fmaxf(fmaxf(s[0][r], s[1][r]), fmaxf(s[2][r], s[3][r]));
    #pragma unroll
    for (int off = 1; off < 16; off <<= 1)
      #pragma unroll
      for (int r = 0; r < 4; r++)
        tm[r] = fmaxf(tm[r], __shfl_xor(tm[r], off));

    float al[4];
    #pragma unroll
    for (int r = 0; r < 4; r++) {
      float mn = fmaxf(m[r], tm[r]);
      al[r] = __expf(m[r] - mn);
      m[r] = mn;
    }
    f32x4 p[4];
    float rs[4] = {0.f, 0.f, 0.f, 0.f};
    #pragma unroll
    for (int n = 0; n < 4; n++)
      #pragma unroll
      for (int r = 0; r < 4; r++) {
        float pv = __expf(s[n][r] - m[r]);
        p[n][r] = pv; rs[r] += pv;
      }
    #pragma unroll
    for (int r = 0; r < 4; r++) l[r] = l[r]*al[r] + rs[r];   // per-lane partial
    #pragma unroll
    for (int n = 0; n < 4; n++)
      #pragma unroll
      for (int r = 0; r < 4; r++) o[n][r] *= al[r];

    // P (C-layout) -> LDS -> A-layout fragments. Per-wave region, no barrier.
    #pragma unroll
    for (int n = 0; n < 4; n++)
      #pragma unroll
      for (int r = 0; r < 4; r++)
        p_lds[wave][g*4 + r][n*16 + c] = __float2bfloat16(p[n][r]);
    s16x8 pa0 = *(const s16x8*)&p_lds[wave][c][g*8];
    s16x8 pa1 = *(const s16x8*)&p_lds[wave][c][32 + g*8];

    #pragma unroll
    for (int n = 0; n < 4; n++) {
      const short* vp = Vb + (size_t)(n*16 + c)*S_ + k0;
      s16x8 vf0 = *(const s16x8*)(vp + g*8);
      s16x8 vf1 = *(const s16x8*)(vp + 32 + g*8);
      o[n] = mfma16x16x32(pa0, vf0, o[n]);
      o[n] = mfma16x16x32(pa1, vf1, o[n]);
    }
  }

  #pragma unroll
  for (int off = 1; off < 16; off <<= 1)
    #pragma unroll
    for (int r = 0; r < 4; r++) l[r] += __shfl_xor(l[r], off);

  bf16* Op = O + (size_t)(b*S_ + q0 + g*4)*D_ + h*DH_;
  #pragma unroll
  for (int r = 0; r < 4; r++) {
    float inv = 1.f / l[r];
    #pragma unroll
    for (int n = 0; n < 4; n++)
      Op[(size_t)r*D_ + n*16 + c] = __float2bfloat16(o[n][r] * inv);
  }
}

// ---------------- residual add + layernorm (in-place on h) ----------------
__global__ __launch_bounds__(256)
void ln_kernel(float* h, const float* __restrict__ delta,
               const float* __restrict__ g, const float* __restrict__ bta,
               bf16* __restrict__ hb)
{
  int row = blockIdx.x;
  float* rp = h + (size_t)row*D_;
  const float* dp = delta + (size_t)row*D_;
  int t = threadIdx.x;
  float v[3];
  float sum = 0.f, sq = 0.f;
  #pragma unroll
  for (int i = 0; i < 3; i++) {
    float xv = rp[t + i*256] + dp[t + i*256];
    v[i] = xv; sum += xv; sq += xv*xv;
  }
  #pragma unroll
  for (int o = 1; o < 64; o <<= 1) { sum += __shfl_xor(sum, o); sq += __shfl_xor(sq, o); }
  __shared__ float ws[8];
  int wave = t >> 6, lane = t & 63;
  if (lane == 0) { ws[wave] = sum; ws[wave+4] = sq; }
  __syncthreads();
  sum = ws[0]+ws[1]+ws[2]+ws[3];
  sq  = ws[4]+ws[5]+ws[6]+ws[7];
  float m   = sum * (1.f/768.f);
  float var = sq * (1.f/768.f) - m*m;
  float rs  = rsqrtf(var + 1e-5f);
  #pragma unroll
  for (int i = 0; i < 3; i++) {
    int idx = t + i*256;
    float y = (v[i] - m) * rs * g[idx] + bta[idx];
    rp[idx] = y;
    hb[(size_t)row*D_ + idx] = __float2bfloat16(y);
  }
}

// ---------------- final projection h[M,768] @ Wout[768,70] + bout ----------
__global__ __launch_bounds__(128)
void final_kernel(const float* __restrict__ h, const float* __restrict__ Wout,
                  const float* __restrict__ bout, float* __restrict__ out)
{
  __shared__ float hs[D_];
  int row = blockIdx.x;
  for (int i = threadIdx.x; i < D_; i += 128) hs[i] = h[(size_t)row*D_ + i];
  __syncthreads();
  int n = threadIdx.x;
  if (n < V_) {
    float acc = bout[n];
    for (int d = 0; d < D_; d++) acc += hs[d] * Wout[d*V_ + n];
    out[(size_t)row*V_ + n] = acc;
  }
}

// ---------------- host launch ----------------
// Workspace ~142 MB: hf 24M + delta 24M + hb 12M + ob 12M +
// shared 48M (union: f1 [48M]  vs  qb+kb+vb+vt [12+12+12+12M]) +
// per-layer wT 14.2M + maskb 2M.
extern "C" void kernel_launch(void* const* d_in, const int* in_sizes, int n_in,
                              void* d_out, int out_size, void* d_ws, size_t ws_size,
                              hipStream_t stream)
{
  (void)in_sizes; (void)n_in; (void)out_size; (void)ws_size;
  const int*   x    = (const int*)d_in[0];
  const int*   mask = (const int*)d_in[1];
  const float* cW   = (const float*)d_in[2];
  const float* sW   = (const float*)d_in[3];
  const float* qW   = (const float*)d_in[4];
  const float* spW  = (const float*)d_in[5];
  const float* Wq   = (const float*)d_in[6];
  const float* Wk   = (const float*)d_in[7];
  const float* Wv   = (const float*)d_in[8];
  const float* Wo   = (const float*)d_in[9];
  const float* bo   = (const float*)d_in[10];
  const float* ln1g = (const float*)d_in[11];
  const float* ln1b = (const float*)d_in[12];
  const float* ln2g = (const float*)d_in[13];
  const float* ln2b = (const float*)d_in[14];
  const float* W1   = (const float*)d_in[15];
  const float* b1   = (const float*)d_in[16];
  const float* W2   = (const float*)d_in[17];
  const float* b2   = (const float*)d_in[18];
  const float* Wout = (const float*)d_in[19];
  const float* bout = (const float*)d_in[20];
  float* out = (float*)d_out;

  char* p = (char*)d_ws;
  auto alloc = [&](size_t bytes) {
    char* r = p; p += (bytes + 1023) & ~(size_t)1023; return r;
  };
  float* hf     = (float*)alloc((size_t)M_*D_*4);
  float* delta  = (float*)alloc((size_t)M_*D_*4);
  bf16*  hb     = (bf16*)alloc((size_t)M_*D_*2);
  bf16*  ob     = (bf16*)alloc((size_t)M_*D_*2);
  char*  shared = alloc((size_t)M_*DFF_*2);      // f1 (48M) / qkv+vt (48M) union
  bf16*  qb     = (bf16*)shared;
  bf16*  kb     = (bf16*)(shared + (size_t)M_*D_*2);
  bf16*  vb     = (bf16*)(shared + (size_t)2*M_*D_*2);
  bf16*  vt     = (bf16*)(shared + (size_t)3*M_*D_*2);   // [B][H][64][S]
  bf16*  f1     = (bf16*)shared;
  bf16*  wqT    = (bf16*)alloc((size_t)D_*D_*2);
  bf16*  wkT    = (bf16*)alloc((size_t)D_*D_*2);
  bf16*  wvT    = (bf16*)alloc((size_t)D_*D_*2);
  bf16*  woT    = (bf16*)alloc((size_t)D_*D_*2);
  bf16*  w1T    = (bf16*)alloc((size_t)D_*DFF_*2);
  bf16*  w2T    = (bf16*)alloc((size_t)DFF_*D_*2);
  bf16*  maskb  = (bf16*)alloc((size_t)S_*S_*2);

  maskb_kernel<<<S_*S_/1024, 256, 0, stream>>>(mask, maskb);
  embed_kernel<<<M_, 256, 0, stream>>>(x, cW, sW, qW, spW, hf, hb);

  for (int l = 0; l < L_; l++) {
    transpose_kernel<<<dim3(12,12), 256, 0, stream>>>(Wq + (size_t)l*D_*D_, wqT, D_, D_);
    transpose_kernel<<<dim3(12,12), 256, 0, stream>>>(Wk + (size_t)l*D_*D_, wkT, D_, D_);
    transpose_kernel<<<dim3(12,12), 256, 0, stream>>>(Wv + (size_t)l*D_*D_, wvT, D_, D_);
    transpose_kernel<<<dim3(12,12), 256, 0, stream>>>(Wo + (size_t)l*D_*D_, woT, D_, D_);
    transpose_kernel<<<dim3(48,12), 256, 0, stream>>>(W1 + (size_t)l*D_*DFF_, w1T, D_, DFF_);
    transpose_kernel<<<dim3(12,48), 256, 0, stream>>>(W2 + (size_t)l*DFF_*D_, w2T, DFF_, D_);

    gemm_kernel<false,false,true><<<dim3(64,6), 256, 0, stream>>>(hb, wqT, nullptr, nullptr, qb, D_, D_);
    gemm_kernel<false,false,true><<<dim3(64,6), 256, 0, stream>>>(hb, wkT, nullptr, nullptr, kb, D_, D_);
    gemm_kernel<false,false,true><<<dim3(64,6), 256, 0, stream>>>(hb, wvT, nullptr, nullptr, vb, D_, D_);

    vT_kernel<<<dim3(16, H_, B_), 256, 0, stream>>>(vb, vt);
    fattn_kernel<<<dim3(S_/64, H_, B_), 256, 0, stream>>>(qb, kb, vt, maskb, ob);

    gemm_kernel<true,false,false><<<dim3(64,6), 256, 0, stream>>>(ob, woT, bo + l*D_, delta, nullptr, D_, D_);
    ln_kernel<<<M_, 256, 0, stream>>>(hf, delta, ln1g + l*D_, ln1b + l*D_, hb);

    gemm_kernel<true,true,true ><<<dim3(64,24), 256, 0, stream>>>(hb, w1T, b1 + l*DFF_, nullptr, f1, DFF_, D_);
    gemm_kernel<true,false,false><<<dim3(64,6), 256, 0, stream>>>(f1, w2T, b2 + l*D_, delta, nullptr, D_, DFF_);
    ln_kernel<<<M_, 256, 0, stream>>>(hf, delta, ln2g + l*D_, ln2b + l*D_, hb);
  }

  final_kernel<<<M_, 128, 0, stream>>>(hf, Wout, bout, out);
}

// Round 4
// 3205.783 us; speedup vs baseline: 4.1527x; 1.0723x over previous
//
#include <hip/hip_runtime.h>
#include <hip/hip_bf16.h>

#define B_   8
#define S_   1024
#define D_   768
#define DFF_ 3072
#define L_   6
#define H_   12
#define DH_  64
#define V_   70
#define M_   (B_*S_)     // 8192 rows
#define QKVLD 2304       // packed q|k|v row stride

typedef __attribute__((ext_vector_type(4))) float  f32x4;
typedef __attribute__((ext_vector_type(8))) short  s16x8;
typedef __attribute__((ext_vector_type(8))) __bf16 bfv8;
typedef __hip_bfloat16 bf16;

__device__ __forceinline__ float b2f(short u) {
  return __uint_as_float(((unsigned)(unsigned short)u) << 16);
}

__device__ __forceinline__ f32x4 mfma16x16x32(s16x8 a, s16x8 b, f32x4 c) {
  return __builtin_amdgcn_mfma_f32_16x16x32_bf16(
      __builtin_bit_cast(bfv8, a), __builtin_bit_cast(bfv8, b), c, 0, 0, 0);
}

__device__ __forceinline__ void gload16(const void* g, void* lds) {
  __builtin_amdgcn_global_load_lds(
      (const __attribute__((address_space(1))) unsigned int*)g,
      (__attribute__((address_space(3))) unsigned int*)lds, 16, 0, 0);
}

// ---------------- embedding + positional encoding ----------------
__global__ __launch_bounds__(256)
void embed_kernel(const int* __restrict__ x,
                  const float* __restrict__ cW, const float* __restrict__ sW,
                  const float* __restrict__ qW, const float* __restrict__ spW,
                  float* __restrict__ hf, bf16* __restrict__ hb)
{
  int tok  = blockIdx.x;          // b*S + s
  int spos = tok & (S_ - 1);
  int t    = x[tok];
  for (int idx = threadIdx.x; idx < D_; idx += 256) {
    float e;
    if (t < 64) {
      int color = t >> 4;       if (color > 3) color = 3;
      int shp   = (t & 15) >> 2;
      int qty   = t & 3;
      e = (idx < 256) ? cW[color*256 + idx]
        : (idx < 512) ? sW[shp*256 + idx - 256]
                      : qW[qty*256 + idx - 512];
    } else {
      int sp = t - 64; if (sp > 5) sp = 5;
      e = spW[sp*D_ + idx];
    }
    int   i2  = idx & ~1;
    float ang = (float)spos * expf(-logf(10000.f) * (float)i2 / (float)D_);
    float pe  = (idx & 1) ? cosf(ang) : sinf(ang);
    float v   = e * 27.712812921102035f + pe;   // sqrt(768)
    hf[(size_t)tok*D_ + idx] = v;
    hb[(size_t)tok*D_ + idx] = __float2bfloat16(v);
  }
}

// ---------------- f32 [K,N] -> bf16 [N,K] ----------------
__global__ __launch_bounds__(256)
void transpose_kernel(const float* __restrict__ in, bf16* __restrict__ out,
                      int K, int N)
{
  __shared__ __align__(16) float s[64][65];
  int n0 = blockIdx.x * 64, k0 = blockIdx.y * 64;
  int tx = threadIdx.x & 63, ty = threadIdx.x >> 6;
  #pragma unroll
  for (int i = 0; i < 16; i++) {
    int r = i*4 + ty;
    s[r][tx] = in[(size_t)(k0 + r)*N + n0 + tx];
  }
  __syncthreads();
  #pragma unroll
  for (int i = 0; i < 16; i++) {
    int r = i*4 + ty;
    out[(size_t)(n0 + r)*K + k0 + tx] = __float2bfloat16(s[tx][r]);
  }
}

// -------- bf16 [b][s][ld-packed h d] -> [b][h][d][s] (V transpose) --------
__global__ __launch_bounds__(256)
void vT_kernel(const bf16* __restrict__ v, int ld, bf16* __restrict__ vt)
{
  __shared__ short tile[64][68];
  int b = blockIdx.z, h = blockIdx.y, s0 = blockIdx.x*64;
  int tr = threadIdx.x >> 4, tc4 = (threadIdx.x & 15)*4;
  #pragma unroll
  for (int i = 0; i < 4; i++) {
    int row = i*16 + tr;
    short4 w = *(const short4*)((const short*)v + (size_t)(b*S_ + s0 + row)*ld + h*DH_ + tc4);
    tile[row][tc4+0]=w.x; tile[row][tc4+1]=w.y; tile[row][tc4+2]=w.z; tile[row][tc4+3]=w.w;
  }
  __syncthreads();
  #pragma unroll
  for (int i = 0; i < 4; i++) {
    int d = i*16 + tr;
    short4 o2;
    o2.x = tile[tc4+0][d]; o2.y = tile[tc4+1][d]; o2.z = tile[tc4+2][d]; o2.w = tile[tc4+3][d];
    *(short4*)((short*)vt + ((size_t)(b*H_ + h)*DH_ + d)*S_ + s0 + tc4) = o2;
  }
}

// ---------------- mask -> additive bf16 bias ----------------
__global__ __launch_bounds__(256)
void maskb_kernel(const int* __restrict__ mask, bf16* __restrict__ mb)
{
  int i = (blockIdx.x*256 + threadIdx.x)*4;
  int4 mv = *(const int4*)(mask + i);
  bf16 z = __float2bfloat16(0.f), ng = __float2bfloat16(-1e9f);
  mb[i+0] = mv.x ? z : ng;
  mb[i+1] = mv.y ? z : ng;
  mb[i+2] = mv.z ? z : ng;
  mb[i+3] = mv.w ? z : ng;
}

// ---------------- per 64x64-tile "has masked entry" flag ----------------
__global__ __launch_bounds__(64)
void mflag_kernel(const int* __restrict__ mask, int* __restrict__ mf)
{
  int qt = blockIdx.x >> 4, kt = blockIdx.x & 15;
  const int* row = mask + (size_t)(qt*64 + threadIdx.x)*S_ + kt*64;
  int allv = 1;
  #pragma unroll
  for (int j = 0; j < 64; j += 4) {
    int4 v = *(const int4*)(row + j);
    allv &= (v.x && v.y && v.z && v.w) ? 1 : 0;
  }
  unsigned long long bal = __ballot(allv);
  if (threadIdx.x == 0) mf[blockIdx.x] = (bal != ~0ULL) ? 1 : 0;
}

// ---------------- GEMM: C[M,N] = A[M,K] @ B, B given as BT[N,K] ------------
// 128x128 tile, BK=32, 4 waves; global_load_lds (width 16) staging,
// m97 2-barrier structure. LDS dest = wave-uniform base + lane*16 (verified).
template<bool BIAS, bool RELU, bool OUTBF16>
__global__ __launch_bounds__(256, 2)
void gemm_kernel(const bf16* __restrict__ A, const bf16* __restrict__ BT,
                 const float* __restrict__ bias,
                 float* __restrict__ Cf, bf16* __restrict__ Cb,
                 int N, int K)
{
  __shared__ __align__(16) short As[4][128][8];
  __shared__ __align__(16) short Bs[4][128][8];
  int t = threadIdx.x;
  int wave = t >> 6, lane = t & 63;
  int wr = wave >> 1, wc = wave & 1;
  int brow = blockIdx.x * 128, bcol = blockIdx.y * 128;
  int r0 = t & 127, kc = t >> 7;
  const short* Ap = (const short*)A + (size_t)(brow + r0)*K + kc*8;
  const short* Bp = (const short*)BT + (size_t)(bcol + r0)*K + kc*8;
  int lr = lane & 15, kg = lane >> 4;

  f32x4 acc[4][4] = {};

  for (int kk = 0; kk < K; kk += 32) {
    __syncthreads();
    gload16(Ap + kk,      &As[kc  ][r0][0]);
    gload16(Ap + kk + 16, &As[kc+2][r0][0]);
    gload16(Bp + kk,      &Bs[kc  ][r0][0]);
    gload16(Bp + kk + 16, &Bs[kc+2][r0][0]);
    __syncthreads();
    s16x8 af[4], bq[4];
    #pragma unroll
    for (int m = 0; m < 4; m++) af[m] = *(const s16x8*)&As[kg][wr*64 + m*16 + lr][0];
    #pragma unroll
    for (int n = 0; n < 4; n++) bq[n] = *(const s16x8*)&Bs[kg][wc*64 + n*16 + lr][0];
    #pragma unroll
    for (int m = 0; m < 4; m++)
      #pragma unroll
      for (int n = 0; n < 4; n++)
        acc[m][n] = mfma16x16x32(af[m], bq[n], acc[m][n]);
  }

  int lg = lane >> 4;
  #pragma unroll
  for (int n = 0; n < 4; n++) {
    int col = bcol + wc*64 + n*16 + lr;
    float bv = 0.f;
    if (BIAS) bv = bias[col];
    #pragma unroll
    for (int m = 0; m < 4; m++) {
      int row0 = brow + wr*64 + m*16 + lg*4;
      #pragma unroll
      for (int r = 0; r < 4; r++) {
        float v = acc[m][n][r] + bv;
        if (RELU) v = fmaxf(v, 0.f);
        size_t off = (size_t)(row0 + r)*N + col;
        if (OUTBF16) Cb[off] = __float2bfloat16(v);
        else         Cf[off] = v;
      }
    }
  }
}

// ---------------- MFMA flash attention ----------------
// grid (S/128, H, B), 4 waves; wave owns 32 q-rows (2 halves u), KV tiles of 64.
// Fragment conventions (verified):
//   A: row = lane&15, k = (lane>>4)*8+j   B: col = lane&15, k = (lane>>4)*8+j
//   C/D: col = lane&15, row = (lane>>4)*4 + reg
__global__ __launch_bounds__(256)
void fattn_kernel(const bf16* __restrict__ QKV, const bf16* __restrict__ Vt,
                  const bf16* __restrict__ Mb, const int* __restrict__ MF,
                  bf16* __restrict__ O)
{
  __shared__ __align__(16) bf16 p_lds[4][32][72];
  int b = blockIdx.z, h = blockIdx.y;
  int wave = threadIdx.x >> 6, lane = threadIdx.x & 63;
  int c = lane & 15, g = lane >> 4;
  int q0 = blockIdx.x*128 + wave*32;

  s16x8 qf[2][2];
  #pragma unroll
  for (int u = 0; u < 2; u++) {
    const short* Qp = (const short*)QKV + (size_t)(b*S_ + q0 + u*16 + c)*QKVLD + h*DH_;
    qf[u][0] = *(const s16x8*)(Qp + g*8);
    qf[u][1] = *(const s16x8*)(Qp + 32 + g*8);
  }
  const short* Kb = (const short*)QKV + (size_t)(b*S_)*QKVLD + D_ + h*DH_;
  const short* Vb = (const short*)Vt + (size_t)(b*H_ + h)*DH_*S_;
  const short* Mp = (const short*)Mb + (size_t)(q0 + g*4)*S_;
  const int*   MFq = MF + (q0 >> 6)*16;      // wave-uniform flag row

  f32x4 o[2][4] = {};
  float m[2][4], l[2][4];
  #pragma unroll
  for (int u = 0; u < 2; u++)
    #pragma unroll
    for (int r = 0; r < 4; r++) { m[u][r] = -3.0e38f; l[u][r] = 0.f; }

  for (int kt = 0; kt < 16; kt++) {
    int k0 = kt*64;
    f32x4 s[2][4];
    #pragma unroll
    for (int n = 0; n < 4; n++) {
      const short* kp = Kb + (size_t)(k0 + n*16 + c)*QKVLD;
      s16x8 kf0 = *(const s16x8*)(kp + g*8);
      s16x8 kf1 = *(const s16x8*)(kp + 32 + g*8);
      #pragma unroll
      for (int u = 0; u < 2; u++) {
        f32x4 z = {};
        z       = mfma16x16x32(qf[u][0], kf0, z);
        s[u][n] = mfma16x16x32(qf[u][1], kf1, z);
      }
    }
    if (MFq[kt]) {
      #pragma unroll
      for (int u = 0; u < 2; u++)
        #pragma unroll
        for (int n = 0; n < 4; n++)
          #pragma unroll
          for (int r = 0; r < 4; r++)
            s[u][n][r] = s[u][n][r]*0.125f
                       + b2f(Mp[(size_t)(u*16 + r)*S_ + k0 + n*16 + c]);
    } else {
      #pragma unroll
      for (int u = 0; u < 2; u++)
        #pragma unroll
        for (int n = 0; n < 4; n++)
          #pragma unroll
          for (int r = 0; r < 4; r++)
            s[u][n][r] *= 0.125f;
    }

    #pragma unroll
    for (int u = 0; u < 2; u++) {
      float tm[4];
      #pragma unroll
      for (int r = 0; r < 4; r++)
        tm[r] = fmaxf(fmaxf(s[u][0][r], s[u][1][r]), fmaxf(s[u][2][r], s[u][3][r]));
      #pragma unroll
      for (int off = 1; off < 16; off <<= 1)
        #pragma unroll
        for (int r = 0; r < 4; r++)
          tm[r] = fmaxf(tm[r], __shfl_xor(tm[r], off));

      float al[4];
      #pragma unroll
      for (int r = 0; r < 4; r++) {
        float mn = fmaxf(m[u][r], tm[r]);
        al[r] = __expf(m[u][r] - mn);
        m[u][r] = mn;
      }
      f32x4 p[4];
      float rs[4] = {0.f, 0.f, 0.f, 0.f};
      #pragma unroll
      for (int n = 0; n < 4; n++)
        #pragma unroll
        for (int r = 0; r < 4; r++) {
          float pv = __expf(s[u][n][r] - m[u][r]);
          p[n][r] = pv; rs[r] += pv;
        }
      #pragma unroll
      for (int r = 0; r < 4; r++) l[u][r] = l[u][r]*al[r] + rs[r];
      #pragma unroll
      for (int n = 0; n < 4; n++)
        #pragma unroll
        for (int r = 0; r < 4; r++) o[u][n][r] *= al[r];
      #pragma unroll
      for (int n = 0; n < 4; n++)
        #pragma unroll
        for (int r = 0; r < 4; r++)
          p_lds[wave][u*16 + g*4 + r][n*16 + c] = __float2bfloat16(p[n][r]);
    }

    s16x8 pa[2][2];
    #pragma unroll
    for (int u = 0; u < 2; u++) {
      pa[u][0] = *(const s16x8*)&p_lds[wave][u*16 + c][g*8];
      pa[u][1] = *(const s16x8*)&p_lds[wave][u*16 + c][32 + g*8];
    }
    #pragma unroll
    for (int n = 0; n < 4; n++) {
      const short* vp = Vb + (size_t)(n*16 + c)*S_ + k0;
      s16x8 vf0 = *(const s16x8*)(vp + g*8);
      s16x8 vf1 = *(const s16x8*)(vp + 32 + g*8);
      #pragma unroll
      for (int u = 0; u < 2; u++) {
        o[u][n] = mfma16x16x32(pa[u][0], vf0, o[u][n]);
        o[u][n] = mfma16x16x32(pa[u][1], vf1, o[u][n]);
      }
    }
  }

  #pragma unroll
  for (int u = 0; u < 2; u++) {
    #pragma unroll
    for (int off = 1; off < 16; off <<= 1)
      #pragma unroll
      for (int r = 0; r < 4; r++) l[u][r] += __shfl_xor(l[u][r], off);
    bf16* Op = O + (size_t)(b*S_ + q0 + u*16 + g*4)*D_ + h*DH_;
    #pragma unroll
    for (int r = 0; r < 4; r++) {
      float inv = 1.f / l[u][r];
      #pragma unroll
      for (int n = 0; n < 4; n++)
        Op[(size_t)r*D_ + n*16 + c] = __float2bfloat16(o[u][n][r] * inv);
    }
  }
}

// ---------------- residual add + layernorm (in-place on h) ----------------
__global__ __launch_bounds__(256)
void ln_kernel(float* h, const float* __restrict__ delta,
               const float* __restrict__ g, const float* __restrict__ bta,
               bf16* __restrict__ hb)
{
  int row = blockIdx.x;
  float* rp = h + (size_t)row*D_;
  const float* dp = delta + (size_t)row*D_;
  int t = threadIdx.x;
  float v[3];
  float sum = 0.f, sq = 0.f;
  #pragma unroll
  for (int i = 0; i < 3; i++) {
    float xv = rp[t + i*256] + dp[t + i*256];
    v[i] = xv; sum += xv; sq += xv*xv;
  }
  #pragma unroll
  for (int o = 1; o < 64; o <<= 1) { sum += __shfl_xor(sum, o); sq += __shfl_xor(sq, o); }
  __shared__ float ws[8];
  int wave = t >> 6, lane = t & 63;
  if (lane == 0) { ws[wave] = sum; ws[wave+4] = sq; }
  __syncthreads();
  sum = ws[0]+ws[1]+ws[2]+ws[3];
  sq  = ws[4]+ws[5]+ws[6]+ws[7];
  float m   = sum * (1.f/768.f);
  float var = sq * (1.f/768.f) - m*m;
  float rs  = rsqrtf(var + 1e-5f);
  #pragma unroll
  for (int i = 0; i < 3; i++) {
    int idx = t + i*256;
    float y = (v[i] - m) * rs * g[idx] + bta[idx];
    rp[idx] = y;
    hb[(size_t)row*D_ + idx] = __float2bfloat16(y);
  }
}

// ---------------- final projection h[M,768] @ Wout[768,70] + bout ----------
__global__ __launch_bounds__(128)
void final_kernel(const float* __restrict__ h, const float* __restrict__ Wout,
                  const float* __restrict__ bout, float* __restrict__ out)
{
  __shared__ float hs[D_];
  int row = blockIdx.x;
  for (int i = threadIdx.x; i < D_; i += 128) hs[i] = h[(size_t)row*D_ + i];
  __syncthreads();
  int n = threadIdx.x;
  if (n < V_) {
    float acc = bout[n];
    for (int d = 0; d < D_; d++) acc += hs[d] * Wout[d*V_ + n];
    out[(size_t)row*V_ + n] = acc;
  }
}

// ---------------- host launch ----------------
// Workspace ~142 MB: hf 25M + delta 25M + hb 12.6M + ob 12.6M +
// shared 50.3M (union: f1 [50.3M]  vs  qkv [37.7M] + vt [12.6M]) +
// wqkvT 3.5M + woT 1.2M + w1T 4.7M + w2T 4.7M + maskb 2M + mflag 1K.
extern "C" void kernel_launch(void* const* d_in, const int* in_sizes, int n_in,
                              void* d_out, int out_size, void* d_ws, size_t ws_size,
                              hipStream_t stream)
{
  (void)in_sizes; (void)n_in; (void)out_size; (void)ws_size;
  const int*   x    = (const int*)d_in[0];
  const int*   mask = (const int*)d_in[1];
  const float* cW   = (const float*)d_in[2];
  const float* sW   = (const float*)d_in[3];
  const float* qW   = (const float*)d_in[4];
  const float* spW  = (const float*)d_in[5];
  const float* Wq   = (const float*)d_in[6];
  const float* Wk   = (const float*)d_in[7];
  const float* Wv   = (const float*)d_in[8];
  const float* Wo   = (const float*)d_in[9];
  const float* bo   = (const float*)d_in[10];
  const float* ln1g = (const float*)d_in[11];
  const float* ln1b = (const float*)d_in[12];
  const float* ln2g = (const float*)d_in[13];
  const float* ln2b = (const float*)d_in[14];
  const float* W1   = (const float*)d_in[15];
  const float* b1   = (const float*)d_in[16];
  const float* W2   = (const float*)d_in[17];
  const float* b2   = (const float*)d_in[18];
  const float* Wout = (const float*)d_in[19];
  const float* bout = (const float*)d_in[20];
  float* out = (float*)d_out;

  char* p = (char*)d_ws;
  auto alloc = [&](size_t bytes) {
    char* r = p; p += (bytes + 1023) & ~(size_t)1023; return r;
  };
  float* hf     = (float*)alloc((size_t)M_*D_*4);
  float* delta  = (float*)alloc((size_t)M_*D_*4);
  bf16*  hb     = (bf16*)alloc((size_t)M_*D_*2);
  bf16*  ob     = (bf16*)alloc((size_t)M_*D_*2);
  char*  shared = alloc((size_t)M_*DFF_*2);         // f1  vs  qkv+vt union
  bf16*  qkv    = (bf16*)shared;                    // [M][2304]
  bf16*  vt     = (bf16*)(shared + (size_t)M_*QKVLD*2);  // [B][H][64][S]
  bf16*  f1     = (bf16*)shared;
  bf16*  wqkvT  = (bf16*)alloc((size_t)QKVLD*D_*2); // [2304][768]
  bf16*  woT    = (bf16*)alloc((size_t)D_*D_*2);
  bf16*  w1T    = (bf16*)alloc((size_t)D_*DFF_*2);
  bf16*  w2T    = (bf16*)alloc((size_t)DFF_*D_*2);
  bf16*  maskb  = (bf16*)alloc((size_t)S_*S_*2);
  int*   mflag  = (int*)alloc(256*4);

  maskb_kernel<<<S_*S_/1024, 256, 0, stream>>>(mask, maskb);
  mflag_kernel<<<256, 64, 0, stream>>>(mask, mflag);
  embed_kernel<<<M_, 256, 0, stream>>>(x, cW, sW, qW, spW, hf, hb);

  for (int l = 0; l < L_; l++) {
    transpose_kernel<<<dim3(12,12), 256, 0, stream>>>(Wq + (size_t)l*D_*D_, wqkvT, D_, D_);
    transpose_kernel<<<dim3(12,12), 256, 0, stream>>>(Wk + (size_t)l*D_*D_, wqkvT + (size_t)D_*D_, D_, D_);
    transpose_kernel<<<dim3(12,12), 256, 0, stream>>>(Wv + (size_t)l*D_*D_, wqkvT + (size_t)2*D_*D_, D_, D_);
    transpose_kernel<<<dim3(12,12), 256, 0, stream>>>(Wo + (size_t)l*D_*D_, woT, D_, D_);
    transpose_kernel<<<dim3(48,12), 256, 0, stream>>>(W1 + (size_t)l*D_*DFF_, w1T, D_, DFF_);
    transpose_kernel<<<dim3(12,48), 256, 0, stream>>>(W2 + (size_t)l*DFF_*D_, w2T, DFF_, D_);

    gemm_kernel<false,false,true><<<dim3(64,18), 256, 0, stream>>>(hb, wqkvT, nullptr, nullptr, qkv, QKVLD, D_);

    vT_kernel<<<dim3(16, H_, B_), 256, 0, stream>>>(qkv + 2*D_, QKVLD, vt);
    fattn_kernel<<<dim3(S_/128, H_, B_), 256, 0, stream>>>(qkv, vt, maskb, mflag, ob);

    gemm_kernel<true,false,false><<<dim3(64,6), 256, 0, stream>>>(ob, woT, bo + l*D_, delta, nullptr, D_, D_);
    ln_kernel<<<M_, 256, 0, stream>>>(hf, delta, ln1g + l*D_, ln1b + l*D_, hb);

    gemm_kernel<true,true,true ><<<dim3(64,24), 256, 0, stream>>>(hb, w1T, b1 + l*DFF_, nullptr, f1, DFF_, D_);
    gemm_kernel<true,false,false><<<dim3(64,6), 256, 0, stream>>>(f1, w2T, b2 + l*D_, delta, nullptr, D_, DFF_);
    ln_kernel<<<M_, 256, 0, stream>>>(hf, delta, ln2g + l*D_, ln2b + l*D_, hb);
  }

  final_kernel<<<M_, 128, 0, stream>>>(hf, Wout, bout, out);
}